// Round 8
// baseline (2460.082 us; speedup 1.0000x reference)
//
#include <hip/hip_runtime.h>

#define NB 256
#define NO 32
#define NEE 32
#define NT 16
#define THREADS 512

typedef const float* __restrict__ fp;

struct Params {
  fp z;
  fp ee1w, ee1b, ee2w, ee2b, ee3w, ee3b;
  fp ne1w, ne1b, ne2w, ne2b, ne3w, ne3b, ne4w, ne4b;
  fp le1w, le1b, le2w, le2b, le3w, le3b;
  fp lt1w, lt1b, lt2w, lt2b, lt3w, lt3b, lt4w, lt4b, lt5w, lt5b;
  float* out;
  int tf;
};

__device__ __forceinline__ float frelu(float x) { return x > 0.f ? x : 0.f; }

// register-file broadcast: value of lane l (compile-time l after unroll)
__device__ __forceinline__ float rl(float v, int l) {
  return __uint_as_float(__builtin_amdgcn_readlane(__float_as_uint(v), l));
}

// LDS float offsets (16000 floats = 62.5 KiB static)
#define OFF_UT  0       // [64][33] u^T (+b1 folded), bank=(h+i)%32 conflict-free
#define OFF_VT  2112    // [64][33] v^T
#define OFF_AG  4224    // [32][64] agg row-major: atomics bank=lane%32 (2-way free)
#define OFF_BN  6272    // 2048: 8 waves x 256 bounce; doubles as A1 src [32][64]
#define OFF_NW  8320    // 7680: lt2(4096) lt3(2048) lt4(512) lt5(1024), resident
#define LDSF    16000

__device__ __forceinline__ void stageN(float* dst, const float* __restrict__ src,
                                       int nf4, int tid) {
  for (int i4 = tid; i4 < nf4; i4 += THREADS)
    *(float4*)(dst + i4 * 4) = *(const float4*)(src + i4 * 4);
}

// 4-row dense; w from GLOBAL (coalesced per-lane col) or LDS (b32, conflict-free);
// x rows are LDS float4 broadcasts. One w read serves 4 rows.
template<int KC>
__device__ __forceinline__ void dense4L(const float* x0, const float* x1,
                                        const float* x2, const float* x3,
                                        const float* __restrict__ w, int ldw,
                                        int col, float o[4]) {
#pragma unroll 4
  for (int kc = 0; kc < KC; ++kc) {
    float w0 = w[(4 * kc + 0) * ldw + col];
    float w1 = w[(4 * kc + 1) * ldw + col];
    float w2 = w[(4 * kc + 2) * ldw + col];
    float w3 = w[(4 * kc + 3) * ldw + col];
    float4 a = *(const float4*)(x0 + 4 * kc);
    float4 b = *(const float4*)(x1 + 4 * kc);
    float4 c = *(const float4*)(x2 + 4 * kc);
    float4 d = *(const float4*)(x3 + 4 * kc);
    o[0] = fmaf(a.x, w0, o[0]); o[0] = fmaf(a.y, w1, o[0]); o[0] = fmaf(a.z, w2, o[0]); o[0] = fmaf(a.w, w3, o[0]);
    o[1] = fmaf(b.x, w0, o[1]); o[1] = fmaf(b.y, w1, o[1]); o[1] = fmaf(b.z, w2, o[1]); o[1] = fmaf(b.w, w3, o[1]);
    o[2] = fmaf(c.x, w0, o[2]); o[2] = fmaf(c.y, w1, o[2]); o[2] = fmaf(c.z, w2, o[2]); o[2] = fmaf(c.w, w3, o[2]);
    o[3] = fmaf(d.x, w0, o[3]); o[3] = fmaf(d.y, w1, o[3]); o[3] = fmaf(d.z, w2, o[3]); o[3] = fmaf(d.w, w3, o[3]);
  }
}

__global__ __launch_bounds__(THREADS) void rld_kernel(Params P) {
  __shared__ float lds[LDSF];
  const int b = blockIdx.x;
  const int tid = (int)threadIdx.x;
  const int lane = tid & 63;
  const int wave = tid >> 6;
  const int cc = lane & 31;
  const int c16 = lane & 15;

  float* UT = lds + OFF_UT;
  float* VT = lds + OFF_VT;
  float* AG = lds + OFF_AG;
  float* sBn = lds + OFF_BN + wave * 256;   // wave-private bounce
  float* src = lds + OFF_BN;                // A1 only (before bounce use)
  const float* wlt2 = lds + OFF_NW;
  const float* wlt3 = lds + OFF_NW + 4096;
  const float* wlt4 = lds + OFF_NW + 6144;
  const float* wlt5 = lds + OFF_NW + 6656;
  const int i0 = wave, i1 = wave + 8, i2 = wave + 16, i3 = wave + 24;
  const int h33 = lane * 33;
  const float* zb = P.z + (size_t)b * NT * NO * NEE;

  // stage step-invariant small node weights once (read from s=1 on)
  stageN(lds + OFF_NW,        P.lt2w, 1024, tid);
  stageN(lds + OFF_NW + 4096, P.lt3w,  512, tid);
  stageN(lds + OFF_NW + 6144, P.lt4w,  128, tid);
  stageN(lds + OFF_NW + 6656, P.lt5w,  256, tid);

  // ===== A1: src[32,512] @ {ee1u, ee1v, ne1src}; 8 chunks of [32][64] =====
  float au[4] = {0,0,0,0}, av[4] = {0,0,0,0}, s1r[4] = {0,0,0,0};
  for (int qq = 0; qq < 8; ++qq) {
    __syncthreads();                    // prior chunk readers done
    for (int idx = tid; idx < 2048; idx += THREADS) {
      int i = idx >> 6, kk = idx & 63;
      int k = qq * 64 + kk, t = k >> 5, e = k & 31;
      float v = zb[(t * NO + i) * NEE + e];
      if (t > 0) v -= zb[((t - 1) * NO + i) * NEE + e];
      src[i * 64 + kk] = v;
    }
    __syncthreads();                    // chunk visible
    for (int c = 0; c < 2; ++c) {
      int r0 = qq * 64 + c * 32;
      const float* x0 = src + i0 * 64 + c * 32;
      const float* x1 = src + i1 * 64 + c * 32;
      const float* x2 = src + i2 * 64 + c * 32;
      const float* x3 = src + i3 * 64 + c * 32;
      dense4L<8>(x0, x1, x2, x3, P.ee1w + (size_t)r0 * 64,         64, lane, au);
      dense4L<8>(x0, x1, x2, x3, P.ee1w + (size_t)(512 + r0) * 64, 64, lane, av);
      dense4L<8>(x0, x1, x2, x3, P.ne1w + (size_t)r0 * 64,         64, lane, s1r);
    }
  }
  {
    float eb1 = P.ee1b[lane];           // fold b1 into u^T
    UT[h33 + i0] = au[0] + eb1; UT[h33 + i1] = au[1] + eb1;
    UT[h33 + i2] = au[2] + eb1; UT[h33 + i3] = au[3] + eb1;
    VT[h33 + i0] = av[0]; VT[h33 + i1] = av[1];
    VT[h33 + i2] = av[2]; VT[h33 + i3] = av[3];
  }
  for (int z = tid; z < 2048; z += THREADS) AG[z] = 0.f;

  float b2c = P.ee2b[lane], b3c = P.ee3b[lane];
  __syncthreads();                      // UT/VT/AG/NW published

  const int tf = P.tf;
  float zci[4] = {0, 0, 0, 0};
  float* outb = P.out + (size_t)b * tf * NO * NEE;

  for (int s = 0; s <= tf; ++s) {
    // ===== pair phase: 64 slots/wave (496 real), batches of 8 pairs;
    // ONE shared 64-reg weight slot, alternately w2 / w3 columns (lane = c).
    // Zero memory in the FMA loops; peak live ~95 VGPR -> no spill. =====
    {
      fp w2p = s ? P.le2w : P.ee2w;
      fp w3p = s ? P.le3w : P.ee3w;
      int pi = 0, rem = wave * 64;
      while (rem >= 31 - pi) { rem -= 31 - pi; ++pi; }   // unrank (triu order)
      int pj = pi + 1 + rem;
      int rank = wave * 64;
      float wslot[64];
#pragma unroll 1
      for (int bt = 0; bt < 8; ++bt) {
        __builtin_amdgcn_sched_barrier(0);   // keep w2 loads out of prior phase B
#pragma unroll
        for (int h = 0; h < 64; ++h) wslot[h] = w2p[h * 64 + lane];
        int ii[8], jj[8]; bool rr[8];
        float x[8];
#pragma unroll
        for (int q = 0; q < 8; ++q) {
          bool real = (rank < 496);
          rr[q] = real;
          ii[q] = real ? pi : 0; jj[q] = real ? pj : 0;
          if (real) { ++pj; if (pj == 32) { ++pi; pj = pi + 1; } }
          ++rank;
          x[q] = fmaxf(UT[h33 + ii[q]] + VT[h33 + jj[q]], 0.f);  // lane = h
        }
        float Y[8];
#pragma unroll
        for (int q = 0; q < 8; ++q) {
          float a0 = b2c, a1 = 0.f;
#pragma unroll
          for (int h = 0; h < 64; h += 2) {
            a0 = fmaf(rl(x[q], h),     wslot[h],     a0);
            a1 = fmaf(rl(x[q], h + 1), wslot[h + 1], a1);
          }
          Y[q] = fmaxf(a0 + a1, 0.f);                            // lane = c
        }
        __builtin_amdgcn_sched_barrier(0);   // keep w3 loads below phase A
#pragma unroll
        for (int h = 0; h < 64; ++h) wslot[h] = w3p[h * 64 + lane];
#pragma unroll
        for (int q = 0; q < 8; ++q) {
          float e0 = b3c, e1 = 0.f;
#pragma unroll
          for (int h = 0; h < 64; h += 2) {
            e0 = fmaf(rl(Y[q], h),     wslot[h],     e0);
            e1 = fmaf(rl(Y[q], h + 1), wslot[h + 1], e1);
          }
          if (rr[q]) {                        // wave-uniform
            float e = e0 + e1;
            atomicAdd(&AG[ii[q] * 64 + lane],  e);
            atomicAdd(&AG[jj[q] * 64 + lane], -e);
          }
        }
      }
    }
    __syncthreads();                    // B1: agg complete

    if (s == 0) {
      // ----- ne node MLP -> zci -----
      float nb1 = P.ne1b[lane], nb2 = P.ne2b[lane];
      float nb3 = P.ne3b[cc],   nb4 = P.ne4b[cc];
      float o1[4] = {s1r[0] + nb1, s1r[1] + nb1, s1r[2] + nb1, s1r[3] + nb1};
      dense4L<16>(AG + i0 * 64, AG + i1 * 64, AG + i2 * 64, AG + i3 * 64,
                  P.ne1w + (size_t)512 * 64, 64, lane, o1);
      sBn[lane] = frelu(o1[0]); sBn[64 + lane] = frelu(o1[1]);
      sBn[128 + lane] = frelu(o1[2]); sBn[192 + lane] = frelu(o1[3]);
      float o2[4] = {nb2, nb2, nb2, nb2};
      dense4L<16>(sBn, sBn + 64, sBn + 128, sBn + 192, P.ne2w, 64, lane, o2);
      sBn[lane] = frelu(o2[0]); sBn[64 + lane] = frelu(o2[1]);
      sBn[128 + lane] = frelu(o2[2]); sBn[192 + lane] = frelu(o2[3]);
      float o3[4] = {nb3, nb3, nb3, nb3};
      dense4L<16>(sBn, sBn + 64, sBn + 128, sBn + 192, P.ne3w, 32, cc, o3);
      sBn[cc] = frelu(o3[0]); sBn[64 + cc] = frelu(o3[1]);
      sBn[128 + cc] = frelu(o3[2]); sBn[192 + cc] = frelu(o3[3]);
      float o4[4] = {nb4, nb4, nb4, nb4};
      dense4L<8>(sBn, sBn + 64, sBn + 128, sBn + 192, P.ne4w, 32, cc, o4);
      zci[0] = (lane < 32) ? zb[(15 * NO + i0) * NEE + lane] : o4[0];
      zci[1] = (lane < 32) ? zb[(15 * NO + i1) * NEE + lane] : o4[1];
      zci[2] = (lane < 32) ? zb[(15 * NO + i2) * NEE + lane] : o4[2];
      zci[3] = (lane < 32) ? zb[(15 * NO + i3) * NEE + lane] : o4[3];
    } else {
      // ----- lt node MLP (sBn holds zci bounce from prep(s-1)) -----
      float lb1 = P.lt1b[lane], lb2 = P.lt2b[lane];
      float lb3 = P.lt3b[cc],   lb4 = P.lt4b[c16], lb5 = P.lt5b[lane];
      float o1[4] = {lb1, lb1, lb1, lb1};
      dense4L<16>(sBn, sBn + 64, sBn + 128, sBn + 192, P.lt1w, 64, lane, o1);
      dense4L<16>(AG + i0 * 64, AG + i1 * 64, AG + i2 * 64, AG + i3 * 64,
                  P.lt1w + (size_t)64 * 64, 64, lane, o1);
      sBn[lane] = frelu(o1[0]); sBn[64 + lane] = frelu(o1[1]);
      sBn[128 + lane] = frelu(o1[2]); sBn[192 + lane] = frelu(o1[3]);
      float o2[4] = {lb2, lb2, lb2, lb2};
      dense4L<16>(sBn, sBn + 64, sBn + 128, sBn + 192, wlt2, 64, lane, o2);
      sBn[lane] = frelu(o2[0]); sBn[64 + lane] = frelu(o2[1]);
      sBn[128 + lane] = frelu(o2[2]); sBn[192 + lane] = frelu(o2[3]);
      float o3[4] = {lb3, lb3, lb3, lb3};
      dense4L<16>(sBn, sBn + 64, sBn + 128, sBn + 192, wlt3, 32, cc, o3);
      sBn[cc] = frelu(o3[0]); sBn[64 + cc] = frelu(o3[1]);
      sBn[128 + cc] = frelu(o3[2]); sBn[192 + cc] = frelu(o3[3]);
      float o4[4] = {lb4, lb4, lb4, lb4};
      dense4L<8>(sBn, sBn + 64, sBn + 128, sBn + 192, wlt4, 16, c16, o4);
      sBn[c16] = frelu(o4[0]); sBn[64 + c16] = frelu(o4[1]);
      sBn[128 + c16] = frelu(o4[2]); sBn[192 + c16] = frelu(o4[3]);
      float o5[4] = {lb5, lb5, lb5, lb5};
      dense4L<4>(sBn, sBn + 64, sBn + 128, sBn + 192, wlt5, 64, lane, o5);
      zci[0] += o5[0]; zci[1] += o5[1]; zci[2] += o5[2]; zci[3] += o5[3];
      int t = s - 1;
      if (lane < 32) {
        outb[(t * NO + i0) * NEE + lane] = zci[0];
        outb[(t * NO + i1) * NEE + lane] = zci[1];
        outb[(t * NO + i2) * NEE + lane] = zci[2];
        outb[(t * NO + i3) * NEE + lane] = zci[3];
      }
    }
    __syncthreads();                    // B2: AG readers done

    if (s < tf) {
      if (s == 0) {                     // switch pair biases ee -> le (once)
        b2c = P.le2b[lane]; b3c = P.le3b[lane];
      }
      for (int z = tid; z < 2048; z += THREADS) AG[z] = 0.f;
      sBn[lane] = zci[0]; sBn[64 + lane] = zci[1];
      sBn[128 + lane] = zci[2]; sBn[192 + lane] = zci[3];
      float gb1 = P.le1b[lane];
      float ou[4] = {0,0,0,0}, ov[4] = {0,0,0,0};
      dense4L<16>(sBn, sBn + 64, sBn + 128, sBn + 192, P.le1w,        64, lane, ou);
      dense4L<16>(sBn, sBn + 64, sBn + 128, sBn + 192, P.le1w + 4096, 64, lane, ov);
      UT[h33 + i0] = ou[0] + gb1; UT[h33 + i1] = ou[1] + gb1;
      UT[h33 + i2] = ou[2] + gb1; UT[h33 + i3] = ou[3] + gb1;
      VT[h33 + i0] = ov[0]; VT[h33 + i1] = ov[1];
      VT[h33 + i2] = ov[2]; VT[h33 + i3] = ov[3];
    }
    __syncthreads();                    // B3: UT/VT + agg-zero published
  }
}

extern "C" void kernel_launch(void* const* d_in, const int* in_sizes, int n_in,
                              void* d_out, int out_size, void* d_ws, size_t ws_size,
                              hipStream_t stream) {
  (void)in_sizes; (void)n_in; (void)d_ws; (void)ws_size;
  Params P;
  int q = 0;
  P.z    = (fp)d_in[q++];
  P.ee1w = (fp)d_in[q++]; P.ee1b = (fp)d_in[q++];
  P.ee2w = (fp)d_in[q++]; P.ee2b = (fp)d_in[q++];
  P.ee3w = (fp)d_in[q++]; P.ee3b = (fp)d_in[q++];
  P.ne1w = (fp)d_in[q++]; P.ne1b = (fp)d_in[q++];
  P.ne2w = (fp)d_in[q++]; P.ne2b = (fp)d_in[q++];
  P.ne3w = (fp)d_in[q++]; P.ne3b = (fp)d_in[q++];
  P.ne4w = (fp)d_in[q++]; P.ne4b = (fp)d_in[q++];
  P.le1w = (fp)d_in[q++]; P.le1b = (fp)d_in[q++];
  P.le2w = (fp)d_in[q++]; P.le2b = (fp)d_in[q++];
  P.le3w = (fp)d_in[q++]; P.le3b = (fp)d_in[q++];
  P.lt1w = (fp)d_in[q++]; P.lt1b = (fp)d_in[q++];
  P.lt2w = (fp)d_in[q++]; P.lt2b = (fp)d_in[q++];
  P.lt3w = (fp)d_in[q++]; P.lt3b = (fp)d_in[q++];
  P.lt4w = (fp)d_in[q++]; P.lt4b = (fp)d_in[q++];
  P.lt5w = (fp)d_in[q++]; P.lt5b = (fp)d_in[q++];
  P.out = (float*)d_out;
  P.tf = out_size / (NB * NO * NEE);
  if (P.tf < 1) P.tf = 1;
  hipLaunchKernelGGL(rld_kernel, dim3(NB), dim3(THREADS), 0, stream, P);
}

// Round 9
// 1164.781 us; speedup vs baseline: 2.1121x; 2.1121x over previous
//
#include <hip/hip_runtime.h>

#define NB 256
#define NO 32
#define NEE 32
#define NT 16
#define THREADS 512

typedef const float* __restrict__ fp;

struct Params {
  fp z;
  fp ee1w, ee1b, ee2w, ee2b, ee3w, ee3b;
  fp ne1w, ne1b, ne2w, ne2b, ne3w, ne3b, ne4w, ne4b;
  fp le1w, le1b, le2w, le2b, le3w, le3b;
  fp lt1w, lt1b, lt2w, lt2b, lt3w, lt3b, lt4w, lt4b, lt5w, lt5b;
  float* out;
  int tf;
};

__device__ __forceinline__ float frelu(float x) { return x > 0.f ? x : 0.f; }

// register-file broadcast: value of lane l (compile-time l after unroll)
__device__ __forceinline__ float rl(float v, int l) {
  return __uint_as_float(__builtin_amdgcn_readlane(__float_as_uint(v), l));
}

// LDS float offsets (16000 floats = 62.5 KiB static)
#define OFF_UT  0       // [64][33] u^T (+b1 folded), bank=(h+i)%32 conflict-free
#define OFF_VT  2112    // [64][33] v^T
#define OFF_AG  4224    // [32][64] agg row-major: atomics bank=lane%32 (2-way free)
#define OFF_BN  6272    // 2048: 8 waves x 256 bounce; doubles as A1 src [32][64]
#define OFF_NW  8320    // 7680: lt2(4096) lt3(2048) lt4(512) lt5(1024), resident
#define LDSF    16000

__device__ __forceinline__ void stageN(float* dst, const float* __restrict__ src,
                                       int nf4, int tid) {
  for (int i4 = tid; i4 < nf4; i4 += THREADS)
    *(float4*)(dst + i4 * 4) = *(const float4*)(src + i4 * 4);
}

// 4-row dense; w from GLOBAL (coalesced per-lane col) or LDS (b32, conflict-free);
// x rows are LDS float4 broadcasts. One w read serves 4 rows.
template<int KC>
__device__ __forceinline__ void dense4L(const float* x0, const float* x1,
                                        const float* x2, const float* x3,
                                        const float* __restrict__ w, int ldw,
                                        int col, float o[4]) {
#pragma unroll 4
  for (int kc = 0; kc < KC; ++kc) {
    float w0 = w[(4 * kc + 0) * ldw + col];
    float w1 = w[(4 * kc + 1) * ldw + col];
    float w2 = w[(4 * kc + 2) * ldw + col];
    float w3 = w[(4 * kc + 3) * ldw + col];
    float4 a = *(const float4*)(x0 + 4 * kc);
    float4 b = *(const float4*)(x1 + 4 * kc);
    float4 c = *(const float4*)(x2 + 4 * kc);
    float4 d = *(const float4*)(x3 + 4 * kc);
    o[0] = fmaf(a.x, w0, o[0]); o[0] = fmaf(a.y, w1, o[0]); o[0] = fmaf(a.z, w2, o[0]); o[0] = fmaf(a.w, w3, o[0]);
    o[1] = fmaf(b.x, w0, o[1]); o[1] = fmaf(b.y, w1, o[1]); o[1] = fmaf(b.z, w2, o[1]); o[1] = fmaf(b.w, w3, o[1]);
    o[2] = fmaf(c.x, w0, o[2]); o[2] = fmaf(c.y, w1, o[2]); o[2] = fmaf(c.z, w2, o[2]); o[2] = fmaf(c.w, w3, o[2]);
    o[3] = fmaf(d.x, w0, o[3]); o[3] = fmaf(d.y, w1, o[3]); o[3] = fmaf(d.z, w2, o[3]); o[3] = fmaf(d.w, w3, o[3]);
  }
}

__global__ __attribute__((amdgpu_waves_per_eu(2, 2)))
__launch_bounds__(THREADS) void rld_kernel(Params P) {
  __shared__ float lds[LDSF];
  const int b = blockIdx.x;
  const int tid = (int)threadIdx.x;
  const int lane = tid & 63;
  const int wave = tid >> 6;
  const int cc = lane & 31;
  const int c16 = lane & 15;

  float* UT = lds + OFF_UT;
  float* VT = lds + OFF_VT;
  float* AG = lds + OFF_AG;
  float* sBn = lds + OFF_BN + wave * 256;   // wave-private bounce
  float* src = lds + OFF_BN;                // A1 only (before bounce use)
  const float* wlt2 = lds + OFF_NW;
  const float* wlt3 = lds + OFF_NW + 4096;
  const float* wlt4 = lds + OFF_NW + 6144;
  const float* wlt5 = lds + OFF_NW + 6656;
  const int i0 = wave, i1 = wave + 8, i2 = wave + 16, i3 = wave + 24;
  const int h33 = lane * 33;
  const float* zb = P.z + (size_t)b * NT * NO * NEE;

  // stage step-invariant small node weights once (read from s=1 on)
  stageN(lds + OFF_NW,        P.lt2w, 1024, tid);
  stageN(lds + OFF_NW + 4096, P.lt3w,  512, tid);
  stageN(lds + OFF_NW + 6144, P.lt4w,  128, tid);
  stageN(lds + OFF_NW + 6656, P.lt5w,  256, tid);

  // ===== A1: src[32,512] @ {ee1u, ee1v, ne1src}; 8 chunks of [32][64] =====
  float au[4] = {0,0,0,0}, av[4] = {0,0,0,0}, s1r[4] = {0,0,0,0};
  for (int qq = 0; qq < 8; ++qq) {
    __syncthreads();                    // prior chunk readers done
    for (int idx = tid; idx < 2048; idx += THREADS) {
      int i = idx >> 6, kk = idx & 63;
      int k = qq * 64 + kk, t = k >> 5, e = k & 31;
      float v = zb[(t * NO + i) * NEE + e];
      if (t > 0) v -= zb[((t - 1) * NO + i) * NEE + e];
      src[i * 64 + kk] = v;
    }
    __syncthreads();                    // chunk visible
    for (int c = 0; c < 2; ++c) {
      int r0 = qq * 64 + c * 32;
      const float* x0 = src + i0 * 64 + c * 32;
      const float* x1 = src + i1 * 64 + c * 32;
      const float* x2 = src + i2 * 64 + c * 32;
      const float* x3 = src + i3 * 64 + c * 32;
      dense4L<8>(x0, x1, x2, x3, P.ee1w + (size_t)r0 * 64,         64, lane, au);
      dense4L<8>(x0, x1, x2, x3, P.ee1w + (size_t)(512 + r0) * 64, 64, lane, av);
      dense4L<8>(x0, x1, x2, x3, P.ne1w + (size_t)r0 * 64,         64, lane, s1r);
    }
  }
  {
    float eb1 = P.ee1b[lane];           // fold b1 into u^T
    UT[h33 + i0] = au[0] + eb1; UT[h33 + i1] = au[1] + eb1;
    UT[h33 + i2] = au[2] + eb1; UT[h33 + i3] = au[3] + eb1;
    VT[h33 + i0] = av[0]; VT[h33 + i1] = av[1];
    VT[h33 + i2] = av[2]; VT[h33 + i3] = av[3];
  }
  for (int z = tid; z < 2048; z += THREADS) AG[z] = 0.f;

  // pair-MLP weight COLUMNS in registers (lane = output channel)
  float w2c[64], w3c[64];
#pragma unroll
  for (int h = 0; h < 64; ++h) w2c[h] = P.ee2w[h * 64 + lane];
#pragma unroll
  for (int h = 0; h < 64; ++h) w3c[h] = P.ee3w[h * 64 + lane];
  float b2c = P.ee2b[lane], b3c = P.ee3b[lane];
  __syncthreads();                      // UT/VT/AG/NW published

  const int tf = P.tf;
  float zci[4] = {0, 0, 0, 0};
  float* outb = P.out + (size_t)b * tf * NO * NEE;

  for (int s = 0; s <= tf; ++s) {
    // ===== pair phase: 62 pairs/wave, 2 at a time; zero loads in inner loops =====
    {
      int pi = 0, rem = wave * 62;
      while (rem >= 31 - pi) { rem -= 31 - pi; ++pi; }
      int pj = pi + 1 + rem;
#pragma unroll 1
      for (int pp = 0; pp < 31; ++pp) {
        const int iA = pi, jA = pj;
        ++pj; if (pj == 32) { ++pi; pj = pi + 1; }
        const int iB = pi, jB = pj;
        ++pj; if (pj == 32) { ++pi; pj = pi + 1; }
        float xA = fmaxf(UT[h33 + iA] + VT[h33 + jA], 0.f);  // lane = h
        float xB = fmaxf(UT[h33 + iB] + VT[h33 + jB], 0.f);
        float a0 = b2c, a1 = 0.f, c0 = b2c, c1 = 0.f;
#pragma unroll
        for (int h = 0; h < 64; h += 2) {
          a0 = fmaf(rl(xA, h),     w2c[h],     a0);
          a1 = fmaf(rl(xA, h + 1), w2c[h + 1], a1);
          c0 = fmaf(rl(xB, h),     w2c[h],     c0);
          c1 = fmaf(rl(xB, h + 1), w2c[h + 1], c1);
        }
        float yA = fmaxf(a0 + a1, 0.f);                      // lane = h for L3
        float yB = fmaxf(c0 + c1, 0.f);
        float e0 = b3c, e1 = 0.f, f0 = b3c, f1 = 0.f;
#pragma unroll
        for (int h = 0; h < 64; h += 2) {
          e0 = fmaf(rl(yA, h),     w3c[h],     e0);
          e1 = fmaf(rl(yA, h + 1), w3c[h + 1], e1);
          f0 = fmaf(rl(yB, h),     w3c[h],     f0);
          f1 = fmaf(rl(yB, h + 1), w3c[h + 1], f1);
        }
        float eA = e0 + e1, eB = f0 + f1;
        atomicAdd(&AG[iA * 64 + lane],  eA);
        atomicAdd(&AG[jA * 64 + lane], -eA);
        atomicAdd(&AG[iB * 64 + lane],  eB);
        atomicAdd(&AG[jB * 64 + lane], -eB);
      }
    }
    __syncthreads();                    // B1: agg complete

    if (s == 0) {
      // ----- ne node MLP -> zci -----
      float nb1 = P.ne1b[lane], nb2 = P.ne2b[lane];
      float nb3 = P.ne3b[cc],   nb4 = P.ne4b[cc];
      float o1[4] = {s1r[0] + nb1, s1r[1] + nb1, s1r[2] + nb1, s1r[3] + nb1};
      dense4L<16>(AG + i0 * 64, AG + i1 * 64, AG + i2 * 64, AG + i3 * 64,
                  P.ne1w + (size_t)512 * 64, 64, lane, o1);
      sBn[lane] = frelu(o1[0]); sBn[64 + lane] = frelu(o1[1]);
      sBn[128 + lane] = frelu(o1[2]); sBn[192 + lane] = frelu(o1[3]);
      float o2[4] = {nb2, nb2, nb2, nb2};
      dense4L<16>(sBn, sBn + 64, sBn + 128, sBn + 192, P.ne2w, 64, lane, o2);
      sBn[lane] = frelu(o2[0]); sBn[64 + lane] = frelu(o2[1]);
      sBn[128 + lane] = frelu(o2[2]); sBn[192 + lane] = frelu(o2[3]);
      float o3[4] = {nb3, nb3, nb3, nb3};
      dense4L<16>(sBn, sBn + 64, sBn + 128, sBn + 192, P.ne3w, 32, cc, o3);
      sBn[cc] = frelu(o3[0]); sBn[64 + cc] = frelu(o3[1]);
      sBn[128 + cc] = frelu(o3[2]); sBn[192 + cc] = frelu(o3[3]);
      float o4[4] = {nb4, nb4, nb4, nb4};
      dense4L<8>(sBn, sBn + 64, sBn + 128, sBn + 192, P.ne4w, 32, cc, o4);
      zci[0] = (lane < 32) ? zb[(15 * NO + i0) * NEE + lane] : o4[0];
      zci[1] = (lane < 32) ? zb[(15 * NO + i1) * NEE + lane] : o4[1];
      zci[2] = (lane < 32) ? zb[(15 * NO + i2) * NEE + lane] : o4[2];
      zci[3] = (lane < 32) ? zb[(15 * NO + i3) * NEE + lane] : o4[3];
    } else {
      // ----- lt node MLP (sBn holds zci bounce from prep(s-1)) -----
      float lb1 = P.lt1b[lane], lb2 = P.lt2b[lane];
      float lb3 = P.lt3b[cc],   lb4 = P.lt4b[c16], lb5 = P.lt5b[lane];
      float o1[4] = {lb1, lb1, lb1, lb1};
      dense4L<16>(sBn, sBn + 64, sBn + 128, sBn + 192, P.lt1w, 64, lane, o1);
      dense4L<16>(AG + i0 * 64, AG + i1 * 64, AG + i2 * 64, AG + i3 * 64,
                  P.lt1w + (size_t)64 * 64, 64, lane, o1);
      sBn[lane] = frelu(o1[0]); sBn[64 + lane] = frelu(o1[1]);
      sBn[128 + lane] = frelu(o1[2]); sBn[192 + lane] = frelu(o1[3]);
      float o2[4] = {lb2, lb2, lb2, lb2};
      dense4L<16>(sBn, sBn + 64, sBn + 128, sBn + 192, wlt2, 64, lane, o2);
      sBn[lane] = frelu(o2[0]); sBn[64 + lane] = frelu(o2[1]);
      sBn[128 + lane] = frelu(o2[2]); sBn[192 + lane] = frelu(o2[3]);
      float o3[4] = {lb3, lb3, lb3, lb3};
      dense4L<16>(sBn, sBn + 64, sBn + 128, sBn + 192, wlt3, 32, cc, o3);
      sBn[cc] = frelu(o3[0]); sBn[64 + cc] = frelu(o3[1]);
      sBn[128 + cc] = frelu(o3[2]); sBn[192 + cc] = frelu(o3[3]);
      float o4[4] = {lb4, lb4, lb4, lb4};
      dense4L<8>(sBn, sBn + 64, sBn + 128, sBn + 192, wlt4, 16, c16, o4);
      sBn[c16] = frelu(o4[0]); sBn[64 + c16] = frelu(o4[1]);
      sBn[128 + c16] = frelu(o4[2]); sBn[192 + c16] = frelu(o4[3]);
      float o5[4] = {lb5, lb5, lb5, lb5};
      dense4L<4>(sBn, sBn + 64, sBn + 128, sBn + 192, wlt5, 64, lane, o5);
      zci[0] += o5[0]; zci[1] += o5[1]; zci[2] += o5[2]; zci[3] += o5[3];
      int t = s - 1;
      if (lane < 32) {
        outb[(t * NO + i0) * NEE + lane] = zci[0];
        outb[(t * NO + i1) * NEE + lane] = zci[1];
        outb[(t * NO + i2) * NEE + lane] = zci[2];
        outb[(t * NO + i3) * NEE + lane] = zci[3];
      }
    }
    __syncthreads();                    // B2: AG readers done

    if (s < tf) {
      if (s == 0) {                     // switch pair weights ee -> le (once)
#pragma unroll
        for (int h = 0; h < 64; ++h) w2c[h] = P.le2w[h * 64 + lane];
#pragma unroll
        for (int h = 0; h < 64; ++h) w3c[h] = P.le3w[h * 64 + lane];
        b2c = P.le2b[lane]; b3c = P.le3b[lane];
      }
      for (int z = tid; z < 2048; z += THREADS) AG[z] = 0.f;
      sBn[lane] = zci[0]; sBn[64 + lane] = zci[1];
      sBn[128 + lane] = zci[2]; sBn[192 + lane] = zci[3];
      float gb1 = P.le1b[lane];
      float ou[4] = {0,0,0,0}, ov[4] = {0,0,0,0};
      dense4L<16>(sBn, sBn + 64, sBn + 128, sBn + 192, P.le1w,        64, lane, ou);
      dense4L<16>(sBn, sBn + 64, sBn + 128, sBn + 192, P.le1w + 4096, 64, lane, ov);
      UT[h33 + i0] = ou[0] + gb1; UT[h33 + i1] = ou[1] + gb1;
      UT[h33 + i2] = ou[2] + gb1; UT[h33 + i3] = ou[3] + gb1;
      VT[h33 + i0] = ov[0]; VT[h33 + i1] = ov[1];
      VT[h33 + i2] = ov[2]; VT[h33 + i3] = ov[3];
    }
    __syncthreads();                    // B3: UT/VT + agg-zero published
  }
}

extern "C" void kernel_launch(void* const* d_in, const int* in_sizes, int n_in,
                              void* d_out, int out_size, void* d_ws, size_t ws_size,
                              hipStream_t stream) {
  (void)in_sizes; (void)n_in; (void)d_ws; (void)ws_size;
  Params P;
  int q = 0;
  P.z    = (fp)d_in[q++];
  P.ee1w = (fp)d_in[q++]; P.ee1b = (fp)d_in[q++];
  P.ee2w = (fp)d_in[q++]; P.ee2b = (fp)d_in[q++];
  P.ee3w = (fp)d_in[q++]; P.ee3b = (fp)d_in[q++];
  P.ne1w = (fp)d_in[q++]; P.ne1b = (fp)d_in[q++];
  P.ne2w = (fp)d_in[q++]; P.ne2b = (fp)d_in[q++];
  P.ne3w = (fp)d_in[q++]; P.ne3b = (fp)d_in[q++];
  P.ne4w = (fp)d_in[q++]; P.ne4b = (fp)d_in[q++];
  P.le1w = (fp)d_in[q++]; P.le1b = (fp)d_in[q++];
  P.le2w = (fp)d_in[q++]; P.le2b = (fp)d_in[q++];
  P.le3w = (fp)d_in[q++]; P.le3b = (fp)d_in[q++];
  P.lt1w = (fp)d_in[q++]; P.lt1b = (fp)d_in[q++];
  P.lt2w = (fp)d_in[q++]; P.lt2b = (fp)d_in[q++];
  P.lt3w = (fp)d_in[q++]; P.lt3b = (fp)d_in[q++];
  P.lt4w = (fp)d_in[q++]; P.lt4b = (fp)d_in[q++];
  P.lt5w = (fp)d_in[q++]; P.lt5b = (fp)d_in[q++];
  P.out = (float*)d_out;
  P.tf = out_size / (NB * NO * NEE);
  if (P.tf < 1) P.tf = 1;
  hipLaunchKernelGGL(rld_kernel, dim3(NB), dim3(THREADS), 0, stream, P);
}